// Round 9
// baseline (305.663 us; speedup 1.0000x reference)
//
#include <hip/hip_runtime.h>
#include <type_traits>
#include <utility>

// ---------------- types ----------------
typedef float f32x4  __attribute__((ext_vector_type(4)));
typedef float f32x16 __attribute__((ext_vector_type(16)));
typedef __bf16 bf16x8 __attribute__((ext_vector_type(8)));
typedef short  s16x8  __attribute__((ext_vector_type(8)));

// ---- mfma 32x32x16 wrapper: robust to builtin operand type ----
template <typename V>
__device__ __forceinline__ f32x16 mfma32_call(V a, V b, f32x16 c) {
  return __builtin_amdgcn_mfma_f32_32x32x16_bf16(a, b, c, 0, 0, 0);
}
template <typename V, typename = void>
struct M32Takes : std::false_type {};
template <typename V>
struct M32Takes<V, std::void_t<decltype(__builtin_amdgcn_mfma_f32_32x32x16_bf16(
    std::declval<V>(), std::declval<V>(), std::declval<f32x16>(), 0, 0, 0))>>
    : std::true_type {};

__device__ __forceinline__ f32x16 MFMA32(uint4 a, uint4 b, f32x16 c) {
  if constexpr (M32Takes<bf16x8>::value) {
    return mfma32_call(__builtin_bit_cast(bf16x8, a), __builtin_bit_cast(bf16x8, b), c);
  } else {
    return mfma32_call(__builtin_bit_cast(s16x8, a), __builtin_bit_cast(s16x8, b), c);
  }
}

// ---------------- f32 -> bf16 via native casts (compiler emits cvt_pk) ----
__device__ __forceinline__ uint4 pk8(float4 x, float4 y) {
  bf16x8 v = {(__bf16)x.x, (__bf16)x.y, (__bf16)x.z, (__bf16)x.w,
              (__bf16)y.x, (__bf16)y.y, (__bf16)y.z, (__bf16)y.w};
  return __builtin_bit_cast(uint4, v);
}
__device__ __forceinline__ unsigned pk2n(float a, float b) {
  unsigned short ua = __builtin_bit_cast(unsigned short, (__bf16)a);
  unsigned short ub = __builtin_bit_cast(unsigned short, (__bf16)b);
  return (unsigned)ua | ((unsigned)ub << 16);
}

// ---------------- problem constants ----------------
constexpr int TS  = 2304;
constexpr int DH  = 64;
constexpr int QTB = 64;          // q rows per block (32 per wave, 2 waves)
constexpr int NQB = TS / QTB;    // 36
constexpr int KVB = 64;          // kv rows per step
constexpr int STR = 72;          // K LDS row stride (shorts): 144B
constexpr float QSCL = 0.125f * 1.4426950408889634f;  // 1/sqrt(64) * log2(e)
constexpr float THR  = 8.0f * 1.4426950408889634f;    // defer-rescale, log2 units
constexpr float NEGBIG = -3.0e38f;

// Pure-causal L-former (round-0 analysis), swapped-QK 32x32 structure (r8,
// HW-verified): S^T = mfma32(A=K, B=Q^T); lane owns P-column for q=lane&31;
// softmax in-register; P->A-frag via cvt_pk + shfl_xor(32).
// r9 deltas: 2-wave blocks (1152 blocks, fine-grain balance), K-only LDS
// double-buffer (18.4 KB -> 8 blocks/CU, 4 waves/SIMD), V read direct from
// global as B-fragments (coalesced, imm-offset), demand staging, 1 barrier/step.
__global__ __launch_bounds__(128, 4) void lformer_attn(
    const float* __restrict__ Qm, const float* __restrict__ Km,
    const float* __restrict__ Vm, float* __restrict__ Om) {
  __shared__ short lk[2][KVB * STR];   // 18,432 B

  const int bid = blockIdx.x;
  const int qt  = (NQB - 1) - (bid >> 5);  // heavy q-blocks first
  const int bh  = bid & 31;
  const int tid = threadIdx.x;
  const int w    = tid >> 6;     // 0..1
  const int lane = tid & 63;
  const int ql   = lane & 31;
  const int hi   = lane >> 5;

  const size_t base = (size_t)bh * TS * DH;
  const int q0  = qt * QTB;
  const int qw0 = q0 + 32 * w;   // this wave's first q row
  const int nkv = qt + 1;        // causal extent in 64-kv tiles

  // K staging map: thread covers half a row (32 f32)
  const int srow  = tid >> 1;
  const int shalf = (tid & 1) * 32;

  auto stage = [&](int step, int buf) {
    const float* kp = Km + base + (size_t)(step * KVB + srow) * DH + shalf;
    short* dst = &lk[buf][srow * STR + shalf];
#pragma unroll
    for (int c = 0; c < 4; ++c) {
      float4 a = *(const float4*)(kp + 8 * c);
      float4 b = *(const float4*)(kp + 8 * c + 4);
      *(uint4*)(dst + 8 * c) = pk8(a, b);
    }
  };

  stage(0, 0);   // loads fly under Q packing

  // ---- Q fragments (B-operand of S^T), pre-scaled by QSCL ----
  uint4 qf[4];
  {
    const float* qp = Qm + base + (size_t)(qw0 + ql) * DH;
#pragma unroll
    for (int c = 0; c < 4; ++c) {
      const int d = 16 * c + 8 * hi;
      float4 x = *(const float4*)(qp + d);
      float4 y = *(const float4*)(qp + d + 4);
      x.x *= QSCL; x.y *= QSCL; x.z *= QSCL; x.w *= QSCL;
      y.x *= QSCL; y.y *= QSCL; y.z *= QSCL; y.w *= QSCL;
      qf[c] = pk8(x, y);
    }
  }

  f32x16 acc[2] = {};            // O[q][d] C/D tiles
  float mrow = NEGBIG;
  float lrow = 0.f;

  const int kb = ql * STR + 8 * hi;   // K LDS read base (shorts)

  auto compute = [&](int step, int buf, auto masked) {
    const int kv0 = step * KVB;
    const short* lkb = lk[buf];

    // ---- S^T = K · Q^T : 2 kv-halves x 4 k-chunks ----
    f32x16 s[2];
#pragma unroll
    for (int nt = 0; nt < 2; ++nt) {
      f32x16 sa = {};
#pragma unroll
      for (int c = 0; c < 4; ++c) {
        const uint4 kf = *(const uint4*)&lkb[kb + nt * 32 * STR + c * 16];
        sa = MFMA32(kf, qf[c], sa);
      }
      s[nt] = sa;
    }

    // ---- mask (diag tiles only) + flatten ----
    float p[32];
    const int qg = qw0 + ql;
#pragma unroll
    for (int nt = 0; nt < 2; ++nt)
#pragma unroll
      for (int r = 0; r < 16; ++r) {
        float x = s[nt][r];
        if constexpr (decltype(masked)::value) {
          const int kvg = kv0 + nt * 32 + (r & 3) + 8 * (r >> 2) + 4 * hi;
          x = (kvg > qg) ? NEGBIG : x;
        }
        p[nt * 16 + r] = x;
      }

    // ---- in-lane max tree + cross-half ----
    float t[16];
#pragma unroll
    for (int r = 0; r < 16; ++r) t[r] = fmaxf(p[r], p[r + 16]);
#pragma unroll
    for (int r = 0; r < 8; ++r) t[r] = fmaxf(t[r], t[r + 8]);
#pragma unroll
    for (int r = 0; r < 4; ++r) t[r] = fmaxf(t[r], t[r + 4]);
    float mx = fmaxf(fmaxf(t[0], t[1]), fmaxf(t[2], t[3]));
    mx = fmaxf(mx, __shfl_xor(mx, 32, 64));

    // ---- defer-rescale (T13) ----
    if (!__all(mx - mrow <= THR)) {
      const float mn = fmaxf(mrow, mx);
      const float a  = exp2f(mrow - mn);
      mrow = mn;
      lrow *= a;
#pragma unroll
      for (int r = 0; r < 16; ++r) {
        const float ar = __shfl(a, (r & 3) + 8 * (r >> 2) + 4 * hi, 64);
        acc[0][r] *= ar;
        acc[1][r] *= ar;
      }
    }

    // ---- P = exp2(S - m); in-lane sum + cross-half ----
#pragma unroll
    for (int r = 0; r < 32; ++r) p[r] = exp2f(p[r] - mrow);
    {
      float u[16];
#pragma unroll
      for (int r = 0; r < 16; ++r) u[r] = p[r] + p[r + 16];
#pragma unroll
      for (int r = 0; r < 8; ++r) u[r] += u[r + 8];
#pragma unroll
      for (int r = 0; r < 4; ++r) u[r] += u[r + 4];
      float ss = (u[0] + u[1]) + (u[2] + u[3]);
      lrow += ss + __shfl_xor(ss, 32, 64);
    }

    // ---- V B-frag bases: direct global, imm-offset loads ----
    const float* vb0 = Vm + base + (size_t)(kv0 + 8 * hi) * DH + ql;
    const float* vb1 = vb0 + 32;

    // ---- P -> A-frags in-register; O += P·V per kv-chunk ----
#pragma unroll
    for (int kc = 0; kc < 4; ++kc) {
      const int b = 8 * kc;
      const unsigned d0 = pk2n(p[b + 0], p[b + 1]);
      const unsigned d1 = pk2n(p[b + 2], p[b + 3]);
      const unsigned d2 = pk2n(p[b + 4], p[b + 5]);
      const unsigned d3 = pk2n(p[b + 6], p[b + 7]);
      const unsigned r1 = __shfl_xor((int)(hi ? d0 : d2), 32, 64);
      const unsigned r2 = __shfl_xor((int)(hi ? d1 : d3), 32, 64);
      uint4 pa;
      pa.x = hi ? r1 : d0;
      pa.y = hi ? r2 : d1;
      pa.z = hi ? d2 : r1;
      pa.w = hi ? d3 : r2;
#pragma unroll
      for (int dt = 0; dt < 2; ++dt) {
        const float* vb = dt ? vb1 : vb0;
        float vv[8];
#pragma unroll
        for (int j = 0; j < 8; ++j) vv[j] = vb[(16 * kc + j) * DH];
        uint4 vf;
        vf.x = pk2n(vv[0], vv[1]);
        vf.y = pk2n(vv[2], vv[3]);
        vf.z = pk2n(vv[4], vv[5]);
        vf.w = pk2n(vv[6], vv[7]);
        acc[dt] = MFMA32(pa, vf, acc[dt]);
      }
    }
  };

  // ---- main loop: demand-staged K dbuf, one barrier per step ----
  __syncthreads();
  int buf = 0;
  for (int step = 0;;) {
    if (step * KVB + KVB - 1 > qw0) compute(step, buf, std::true_type{});
    else                            compute(step, buf, std::false_type{});
    if (++step == nkv) break;
    stage(step, buf ^ 1);
    __syncthreads();
    buf ^= 1;
  }

  // ---- epilogue: gather 1/l per C/D row, coalesced stores ----
  const float inv = 1.0f / lrow;
  float* op = Om + base;
#pragma unroll
  for (int r = 0; r < 16; ++r) {
    const int row = (r & 3) + 8 * (r >> 2) + 4 * hi;
    const float ir = __shfl(inv, row, 64);
#pragma unroll
    for (int dt = 0; dt < 2; ++dt)
      op[(size_t)(qw0 + row) * DH + 32 * dt + ql] = acc[dt][r] * ir;
  }
}

extern "C" void kernel_launch(void* const* d_in, const int* in_sizes, int n_in,
                              void* d_out, int out_size, void* d_ws, size_t ws_size,
                              hipStream_t stream) {
  (void)in_sizes; (void)n_in; (void)d_ws; (void)ws_size; (void)out_size;
  const float* q = (const float*)d_in[0];
  const float* k = (const float*)d_in[1];
  const float* v = (const float*)d_in[2];
  float* o = (float*)d_out;
  lformer_attn<<<dim3(NQB * 32), dim3(128), 0, stream>>>(q, k, v, o);
}